// Round 7
// baseline (1041.835 us; speedup 1.0000x reference)
//
#include <hip/hip_runtime.h>
#include <hip/hip_bf16.h>

typedef __attribute__((ext_vector_type(8))) _Float16 half8;
typedef __attribute__((ext_vector_type(4))) _Float16 half4;
typedef __attribute__((ext_vector_type(2))) unsigned uint2v;
typedef __attribute__((ext_vector_type(4))) float f32x4;

#define B_ 32
#define N_ 1024
#define DIN_ 512
#define H_ 8
#define DH_ 64

// tanh(x) = 1 - 2/(exp(2x)+1); inf/denorm behavior gives exact +-1 saturation,
// tanh(0) == 0 exactly. 3 VALU + 2 trans, no clamp needed.
__device__ __forceinline__ float tanh_e(float x) {
    float e = __builtin_amdgcn_exp2f(x * 2.885390081777927f);  // exp(2x)
    float r = __builtin_amdgcn_rcpf(e + 1.f);
    return fmaf(-2.f, r, 1.f);
}

// pack 4 f32 -> half4 via v_cvt_pkrtz (1 op per pair)
__device__ __forceinline__ half4 pack4(float a, float b, float c, float d) {
    auto lo = __builtin_amdgcn_cvt_pkrtz(a, b);
    auto hi = __builtin_amdgcn_cvt_pkrtz(c, d);
    uint2v u = { __builtin_bit_cast(unsigned, lo), __builtin_bit_cast(unsigned, hi) };
    return __builtin_bit_cast(half4, u);
}

// ---------------- kernel 1: pack adjacency into bitmask -------------------
// A: [B,N,N] f32 of {0,1}  ->  Abits: [B*N][16] u64 (bit m&63 of word m>>6)
__global__ __launch_bounds__(256) void pack_mask(const float* __restrict__ A,
                                                 unsigned long long* __restrict__ Abits) {
    int tid = blockIdx.x * 256 + threadIdx.x;
    int wave = tid >> 6;
    int lane = threadIdx.x & 63;
    float a = A[(size_t)wave * 64 + lane];
    unsigned long long m = __ballot(a != 0.f);
    if (lane == 0) Abits[wave] = m;
}

// ---------------- kernel 2: prep weights (transpose + f16 cast) -----------
// WT: [H*DH][DIN] f16  (WT[h*64+n][k] = Wp[h][k][n]);  Cb: [H][DH][DH] f16
__global__ __launch_bounds__(256) void prep_w(const float* __restrict__ Wp,
                                              const float* __restrict__ C,
                                              _Float16* __restrict__ WT,
                                              _Float16* __restrict__ Cb) {
    int gid = blockIdx.x * 256 + threadIdx.x;
    if (gid < H_ * DH_ * DIN_) {
        int h = gid >> 15;           // DH_*DIN_ = 32768
        int n = (gid >> 9) & 63;
        int k = gid & 511;
        WT[gid] = (_Float16)Wp[((size_t)(h * DIN_ + k)) * DH_ + n];
    } else {
        int cid = gid - H_ * DH_ * DIN_;
        if (cid < H_ * DH_ * DH_) Cb[cid] = (_Float16)C[cid];
    }
}

// ---------------- kernel 3: projection GEMM (all 4 heads per block) -------
// block = (b, n0, half): 64 rows x 256 cols (4 heads, 1 head per wave).
// X tile staged once in LDS (f16), W fragments read from L2-resident WT.
__global__ __launch_bounds__(256) void proj_gemm(const float* __restrict__ X,
                                                 const float* __restrict__ bp,
                                                 const _Float16* __restrict__ WT,
                                                 _Float16* __restrict__ Xp) {
    __shared__ _Float16 Xb[64][72];

    int tid = threadIdx.x;
    int lane = tid & 63, w = tid >> 6;
    int blk = blockIdx.x;
    int b = blk >> 5;
    int n0 = ((blk >> 1) & 15) * 64;
    int h = (blk & 1) * 4 + w;       // head handled by this wave

    int r = tid >> 2, q = tid & 3;
    const float* xrow = X + ((size_t)b * N_ + n0 + r) * DIN_ + q * 16;

    f32x4 acc[4][4] = {};

    for (int kc = 0; kc < 8; ++kc) {
        // stage X[64][64] chunk -> f16
        float4 v0 = *(const float4*)(xrow + kc * 64 + 0);
        float4 v1 = *(const float4*)(xrow + kc * 64 + 4);
        float4 v2 = *(const float4*)(xrow + kc * 64 + 8);
        float4 v3 = *(const float4*)(xrow + kc * 64 + 12);
        half8 h0 = {(_Float16)v0.x, (_Float16)v0.y, (_Float16)v0.z, (_Float16)v0.w,
                    (_Float16)v1.x, (_Float16)v1.y, (_Float16)v1.z, (_Float16)v1.w};
        half8 h1 = {(_Float16)v2.x, (_Float16)v2.y, (_Float16)v2.z, (_Float16)v2.w,
                    (_Float16)v3.x, (_Float16)v3.y, (_Float16)v3.z, (_Float16)v3.w};
        *(half8*)&Xb[r][q * 16] = h0;
        *(half8*)&Xb[r][q * 16 + 8] = h1;
        __syncthreads();

#pragma unroll
        for (int ks = 0; ks < 2; ++ks) {
            half8 a[4];
#pragma unroll
            for (int m = 0; m < 4; ++m)
                a[m] = *(const half8*)&Xb[m * 16 + (lane & 15)][ks * 32 + (lane >> 4) * 8];
#pragma unroll
            for (int f = 0; f < 4; ++f) {
                half8 bb = *(const half8*)(WT + ((size_t)(h * 64 + f * 16 + (lane & 15))) * DIN_
                                           + kc * 64 + ks * 32 + (lane >> 4) * 8);
#pragma unroll
                for (int m = 0; m < 4; ++m)
                    acc[m][f] = __builtin_amdgcn_mfma_f32_16x16x32_f16(a[m], bb, acc[m][f], 0, 0, 0);
            }
        }
        __syncthreads();
    }

    // epilogue: bias + f16 write (coalesced 32B segments per 16-lane group)
    size_t bh = (size_t)(b * 8 + h);
#pragma unroll
    for (int f = 0; f < 4; ++f) {
        int col = f * 16 + (lane & 15);
        float bias = bp[h * 64 + col];
#pragma unroll
        for (int m = 0; m < 4; ++m) {
            int row = m * 16 + ((lane >> 4) << 2);
#pragma unroll
            for (int j = 0; j < 4; ++j) {
                Xp[(bh * N_ + n0 + row + j) * DH_ + col] = (_Float16)(acc[m][f][j] + bias);
            }
        }
    }
}

// ---------------- kernel 3b: bilinear + transpose -------------------------
// per block (bh, n0): Xc = Xp_tile @ C^T ; XpT[bh][d][n] = Xp[bh][n][d]
__global__ __launch_bounds__(256) void bil_kernel(const _Float16* __restrict__ Xp,
                                                  const _Float16* __restrict__ Cb,
                                                  _Float16* __restrict__ Xc,
                                                  _Float16* __restrict__ XpT) {
    __shared__ _Float16 Xs[64][72];

    int tid = threadIdx.x;
    int lane = tid & 63, w = tid >> 6;
    int blk = blockIdx.x;
    int bh = blk >> 4;
    int n0 = (blk & 15) * 64;
    int h = bh & 7;

    int r = tid >> 2, q = tid & 3;
    const half8* src = (const half8*)(Xp + ((size_t)bh * N_ + n0 + r) * DH_ + q * 16);
    *(half8*)&Xs[r][q * 16] = src[0];
    *(half8*)&Xs[r][q * 16 + 8] = src[1];
    __syncthreads();

    // bilinear: rows w*16..w*16+15
    f32x4 acc[4] = {{0,0,0,0},{0,0,0,0},{0,0,0,0},{0,0,0,0}};
#pragma unroll
    for (int ks = 0; ks < 2; ++ks) {
        half8 a = *(const half8*)&Xs[w * 16 + (lane & 15)][ks * 32 + (lane >> 4) * 8];
#pragma unroll
        for (int f = 0; f < 4; ++f) {
            half8 bb = *(const half8*)(Cb + ((size_t)(h * DH_ + f * 16 + (lane & 15))) * DH_
                                       + ks * 32 + (lane >> 4) * 8);
            acc[f] = __builtin_amdgcn_mfma_f32_16x16x32_f16(a, bb, acc[f], 0, 0, 0);
        }
    }
    int rb = w * 16 + ((lane >> 4) << 2);
#pragma unroll
    for (int f = 0; f < 4; ++f) {
        int col = f * 16 + (lane & 15);
#pragma unroll
        for (int j = 0; j < 4; ++j)
            Xc[((size_t)bh * N_ + n0 + rb + j) * DH_ + col] = (_Float16)acc[f][j];
    }

    // transpose: lane-permuted d => row-uniform LDS reads (conflict-free)
    {
        int d = (lane & 3) * 16 + (lane >> 2);
        __align__(16) _Float16 tmp[16];
#pragma unroll
        for (int i = 0; i < 16; ++i) tmp[i] = Xs[w * 16 + i][d];
        _Float16* dst = XpT + ((size_t)bh * DH_ + d) * N_ + n0 + w * 16;
        *(half8*)dst = *(half8*)tmp;
        *(half8*)(dst + 8) = *(half8*)(tmp + 8);
    }
}

// ---------------- kernel 4: fused masked-tanh attention (no LDS) ----------
// per block: (b,h,q0), 4 waves x 16 q-rows.
// S^T = mfma(K_frag, Q_frag): lane holds P-row for q = lane&15,
// kv = f*16 + (lane>>4)*4 + j  == exactly the A-frag layout of
// mfma_f32_16x16x16f16 -> P stays in registers, zero LDS, zero barriers.
__global__ __launch_bounds__(256) void attn_kernel(const _Float16* __restrict__ Xp,
                                                   const _Float16* __restrict__ Xc,
                                                   const _Float16* __restrict__ XpT,
                                                   const unsigned long long* __restrict__ Abits,
                                                   float* __restrict__ out) {
    int tid = threadIdx.x;
    int lane = tid & 63, w = tid >> 6;
    int hi = lane >> 4;
    int c16 = lane & 15;
    int blk = blockIdx.x;
    int bh = blk >> 4;
    int q0 = (blk & 15) * 64;
    int b = bh >> 3, h = bh & 7;

    // Q fragments (B-operand of S^T): row q = q0 + w*16 + c16 of Xc
    const _Float16* qbase = Xc + ((size_t)bh * N_ + q0 + w * 16 + c16) * DH_ + hi * 8;
    half8 qa0 = *(const half8*)qbase;
    half8 qa1 = *(const half8*)(qbase + 32);

    // per-mt base pointers
    const _Float16* kbase = Xp + ((size_t)bh * N_ + c16) * DH_ + hi * 8;      // + mt*4096 + f*1024 (+32)
    const _Float16* vb0 = XpT + ((size_t)bh * DH_ + 0  + c16) * N_ + hi * 4;  // + mt*64 + f*16
    const _Float16* vb1 = XpT + ((size_t)bh * DH_ + 16 + c16) * N_ + hi * 4;
    const _Float16* vb2 = XpT + ((size_t)bh * DH_ + 32 + c16) * N_ + hi * 4;
    const _Float16* vb3 = XpT + ((size_t)bh * DH_ + 48 + c16) * N_ + hi * 4;
    const unsigned long long* mbase = Abits + ((size_t)b * N_ + q0 + w * 16 + c16) * 16;

    f32x4 oacc[4] = {{0,0,0,0},{0,0,0,0},{0,0,0,0},{0,0,0,0}};

    for (int mt = 0; mt < 16; ++mt) {
        const _Float16* kmt = kbase + mt * 4096;   // 64 rows * DH_
        // S^T = K @ Q^T : A = K rows (kv = f*16 + c16), B = Q rows (q = c16)
        f32x4 s[4] = {{0,0,0,0},{0,0,0,0},{0,0,0,0},{0,0,0,0}};
#pragma unroll
        for (int f = 0; f < 4; ++f) {
            half8 k0 = *(const half8*)(kmt + f * 1024);
            half8 k1 = *(const half8*)(kmt + f * 1024 + 32);
            s[f] = __builtin_amdgcn_mfma_f32_16x16x32_f16(k0, qa0, s[f], 0, 0, 0);
            s[f] = __builtin_amdgcn_mfma_f32_16x16x32_f16(k1, qa1, s[f], 0, 0, 0);
        }

        // V fragments for PV (B-operand of 16x16x16): V^T[d][kv] 4-contiguous
        half4 vf0[4], vf1[4], vf2[4], vf3[4];
#pragma unroll
        for (int f = 0; f < 4; ++f) {
            vf0[f] = *(const half4*)(vb0 + mt * 64 + f * 16);
            vf1[f] = *(const half4*)(vb1 + mt * 64 + f * 16);
            vf2[f] = *(const half4*)(vb2 + mt * 64 + f * 16);
            vf3[f] = *(const half4*)(vb3 + mt * 64 + f * 16);
        }

        // mask word: one u64 per q-row per mt; bit index = f*16 + hi*4 + j
        unsigned long long m64 = mbase[mt] >> (hi * 4);
        unsigned mlo = (unsigned)m64;
        unsigned mhi32 = (unsigned)(m64 >> 32);

        // tanh + mask + pack into PV A-fragments (all in registers)
        half4 pa[4];
#pragma unroll
        for (int f = 0; f < 4; ++f) {
            unsigned dw = (f & 2) ? mhi32 : mlo;
            int bb = (f & 1) * 16;
            float t0 = tanh_e(s[f][0]) * (float)((dw >> bb) & 1u);
            float t1 = tanh_e(s[f][1]) * (float)((dw >> (bb + 1)) & 1u);
            float t2 = tanh_e(s[f][2]) * (float)((dw >> (bb + 2)) & 1u);
            float t3 = tanh_e(s[f][3]) * (float)((dw >> (bb + 3)) & 1u);
            pa[f] = pack4(t0, t1, t2, t3);
        }

        // O += P @ V  (16 x mfma_16x16x16, K-slice f)
#pragma unroll
        for (int f = 0; f < 4; ++f) {
            oacc[0] = __builtin_amdgcn_mfma_f32_16x16x16f16(pa[f], vf0[f], oacc[0], 0, 0, 0);
            oacc[1] = __builtin_amdgcn_mfma_f32_16x16x16f16(pa[f], vf1[f], oacc[1], 0, 0, 0);
            oacc[2] = __builtin_amdgcn_mfma_f32_16x16x16f16(pa[f], vf2[f], oacc[2], 0, 0, 0);
            oacc[3] = __builtin_amdgcn_mfma_f32_16x16x16f16(pa[f], vf3[f], oacc[3], 0, 0, 0);
        }
    }

    // epilogue: relu, coalesced f32 writes; oacc row = q-within-wave, col = d
    int rb = w * 16 + hi * 4;
#pragma unroll
    for (int fo = 0; fo < 4; ++fo) {
        int col = h * DH_ + fo * 16 + c16;
#pragma unroll
        for (int j = 0; j < 4; ++j) {
            out[((size_t)b * N_ + q0 + rb + j) * 512 + col] = fmaxf(oacc[fo][j], 0.f);
        }
    }
}

extern "C" void kernel_launch(void* const* d_in, const int* in_sizes, int n_in,
                              void* d_out, int out_size, void* d_ws, size_t ws_size,
                              hipStream_t stream) {
    const float* X  = (const float*)d_in[0];
    const float* A  = (const float*)d_in[1];
    const float* Wp = (const float*)d_in[2];
    const float* bp = (const float*)d_in[3];
    const float* C  = (const float*)d_in[4];
    float* out = (float*)d_out;

    char* ws = (char*)d_ws;
    unsigned long long* Abits = (unsigned long long*)ws;               // 4 MB
    _Float16* WT  = (_Float16*)(ws + 4u * 1024 * 1024);                // 512 KB
    _Float16* Cb  = (_Float16*)(ws + 4u * 1024 * 1024 + 512 * 1024);   // 64 KB
    _Float16* Xp  = (_Float16*)(ws + 5u * 1024 * 1024);                // 32 MB
    _Float16* Xc  = (_Float16*)(ws + 37u * 1024 * 1024);               // 32 MB
    _Float16* XpT = (_Float16*)(ws + 69u * 1024 * 1024);               // 32 MB  (end: 101 MB)

    pack_mask<<<(B_ * N_ * N_) / (64 * 4), 256, 0, stream>>>(A, Abits);
    prep_w<<<(H_ * DH_ * DIN_ + H_ * DH_ * DH_ + 255) / 256, 256, 0, stream>>>(Wp, C, WT, Cb);
    proj_gemm<<<B_ * 16 * 2, 256, 0, stream>>>(X, bp, WT, Xp);
    bil_kernel<<<B_ * H_ * 16, 256, 0, stream>>>(Xp, Cb, Xc, XpT);
    attn_kernel<<<B_ * H_ * 16, 256, 0, stream>>>(Xp, Xc, XpT, Abits, out);
}

// Round 8
// 477.117 us; speedup vs baseline: 2.1836x; 2.1836x over previous
//
#include <hip/hip_runtime.h>
#include <hip/hip_bf16.h>

typedef __attribute__((ext_vector_type(8))) _Float16 half8;
typedef __attribute__((ext_vector_type(4))) _Float16 half4;
typedef __attribute__((ext_vector_type(2))) unsigned uint2v;
typedef __attribute__((ext_vector_type(4))) float f32x4;

#define B_ 32
#define N_ 1024
#define DIN_ 512
#define H_ 8
#define DH_ 64

// tanh(x) = 1 - 2/(exp(2x)+1); inf/denorm behavior gives exact +-1 saturation,
// tanh(0) == 0 exactly. 3 VALU + 2 trans, no clamp needed.
__device__ __forceinline__ float tanh_e(float x) {
    float e = __builtin_amdgcn_exp2f(x * 2.885390081777927f);  // exp(2x)
    float r = __builtin_amdgcn_rcpf(e + 1.f);
    return fmaf(-2.f, r, 1.f);
}

// pack 4 f32 -> half4 via v_cvt_pkrtz (1 op per pair)
__device__ __forceinline__ half4 pack4(float a, float b, float c, float d) {
    auto lo = __builtin_amdgcn_cvt_pkrtz(a, b);
    auto hi = __builtin_amdgcn_cvt_pkrtz(c, d);
    uint2v u = { __builtin_bit_cast(unsigned, lo), __builtin_bit_cast(unsigned, hi) };
    return __builtin_bit_cast(half4, u);
}

// ---------------- kernel 1: pack adjacency into bitmask -------------------
// A: [B,N,N] f32 of {0,1}  ->  Abits: [B*N][16] u64 (bit m&63 of word m>>6)
__global__ __launch_bounds__(256) void pack_mask(const float* __restrict__ A,
                                                 unsigned long long* __restrict__ Abits) {
    int tid = blockIdx.x * 256 + threadIdx.x;
    int wave = tid >> 6;
    int lane = threadIdx.x & 63;
    float a = A[(size_t)wave * 64 + lane];
    unsigned long long m = __ballot(a != 0.f);
    if (lane == 0) Abits[wave] = m;
}

// ---------------- kernel 2: prep weights (transpose + f16 cast) -----------
// WT: [H*DH][DIN] f16  (WT[h*64+n][k] = Wp[h][k][n]);  Cb: [H][DH][DH] f16
__global__ __launch_bounds__(256) void prep_w(const float* __restrict__ Wp,
                                              const float* __restrict__ C,
                                              _Float16* __restrict__ WT,
                                              _Float16* __restrict__ Cb) {
    int gid = blockIdx.x * 256 + threadIdx.x;
    if (gid < H_ * DH_ * DIN_) {
        int h = gid >> 15;           // DH_*DIN_ = 32768
        int n = (gid >> 9) & 63;
        int k = gid & 511;
        WT[gid] = (_Float16)Wp[((size_t)(h * DIN_ + k)) * DH_ + n];
    } else {
        int cid = gid - H_ * DH_ * DIN_;
        if (cid < H_ * DH_ * DH_) Cb[cid] = (_Float16)C[cid];
    }
}

// ---------------- kernel 3: projection GEMM (all 4 heads per block) -------
// block = (b, n0, half): 64 rows x 256 cols (4 heads, 1 head per wave).
// X tile staged once in LDS (f16), W fragments read from L2-resident WT.
__global__ __launch_bounds__(256) void proj_gemm(const float* __restrict__ X,
                                                 const float* __restrict__ bp,
                                                 const _Float16* __restrict__ WT,
                                                 _Float16* __restrict__ Xp) {
    __shared__ _Float16 Xb[64][72];

    int tid = threadIdx.x;
    int lane = tid & 63, w = tid >> 6;
    int blk = blockIdx.x;
    int b = blk >> 5;
    int n0 = ((blk >> 1) & 15) * 64;
    int h = (blk & 1) * 4 + w;       // head handled by this wave

    int r = tid >> 2, q = tid & 3;
    const float* xrow = X + ((size_t)b * N_ + n0 + r) * DIN_ + q * 16;

    f32x4 acc[4][4] = {};

    for (int kc = 0; kc < 8; ++kc) {
        // stage X[64][64] chunk -> f16
        float4 v0 = *(const float4*)(xrow + kc * 64 + 0);
        float4 v1 = *(const float4*)(xrow + kc * 64 + 4);
        float4 v2 = *(const float4*)(xrow + kc * 64 + 8);
        float4 v3 = *(const float4*)(xrow + kc * 64 + 12);
        half8 h0 = {(_Float16)v0.x, (_Float16)v0.y, (_Float16)v0.z, (_Float16)v0.w,
                    (_Float16)v1.x, (_Float16)v1.y, (_Float16)v1.z, (_Float16)v1.w};
        half8 h1 = {(_Float16)v2.x, (_Float16)v2.y, (_Float16)v2.z, (_Float16)v2.w,
                    (_Float16)v3.x, (_Float16)v3.y, (_Float16)v3.z, (_Float16)v3.w};
        *(half8*)&Xb[r][q * 16] = h0;
        *(half8*)&Xb[r][q * 16 + 8] = h1;
        __syncthreads();

#pragma unroll
        for (int ks = 0; ks < 2; ++ks) {
            half8 a[4];
#pragma unroll
            for (int m = 0; m < 4; ++m)
                a[m] = *(const half8*)&Xb[m * 16 + (lane & 15)][ks * 32 + (lane >> 4) * 8];
#pragma unroll
            for (int f = 0; f < 4; ++f) {
                half8 bb = *(const half8*)(WT + ((size_t)(h * 64 + f * 16 + (lane & 15))) * DIN_
                                           + kc * 64 + ks * 32 + (lane >> 4) * 8);
#pragma unroll
                for (int m = 0; m < 4; ++m)
                    acc[m][f] = __builtin_amdgcn_mfma_f32_16x16x32_f16(a[m], bb, acc[m][f], 0, 0, 0);
            }
        }
        __syncthreads();
    }

    // epilogue: bias + f16 write (coalesced 32B segments per 16-lane group)
    size_t bh = (size_t)(b * 8 + h);
#pragma unroll
    for (int f = 0; f < 4; ++f) {
        int col = f * 16 + (lane & 15);
        float bias = bp[h * 64 + col];
#pragma unroll
        for (int m = 0; m < 4; ++m) {
            int row = m * 16 + ((lane >> 4) << 2);
#pragma unroll
            for (int j = 0; j < 4; ++j) {
                Xp[(bh * N_ + n0 + row + j) * DH_ + col] = (_Float16)(acc[m][f][j] + bias);
            }
        }
    }
}

// ---------------- kernel 3b: bilinear + transpose -------------------------
// per block (bh, n0): Xc = Xp_tile @ C^T ; XpT[bh][d][n] = Xp[bh][n][d]
__global__ __launch_bounds__(256) void bil_kernel(const _Float16* __restrict__ Xp,
                                                  const _Float16* __restrict__ Cb,
                                                  _Float16* __restrict__ Xc,
                                                  _Float16* __restrict__ XpT) {
    __shared__ _Float16 Xs[64][72];

    int tid = threadIdx.x;
    int lane = tid & 63, w = tid >> 6;
    int blk = blockIdx.x;
    int bh = blk >> 4;
    int n0 = (blk & 15) * 64;
    int h = bh & 7;

    int r = tid >> 2, q = tid & 3;
    const half8* src = (const half8*)(Xp + ((size_t)bh * N_ + n0 + r) * DH_ + q * 16);
    *(half8*)&Xs[r][q * 16] = src[0];
    *(half8*)&Xs[r][q * 16 + 8] = src[1];
    __syncthreads();

    // bilinear: rows w*16..w*16+15
    f32x4 acc[4] = {{0,0,0,0},{0,0,0,0},{0,0,0,0},{0,0,0,0}};
#pragma unroll
    for (int ks = 0; ks < 2; ++ks) {
        half8 a = *(const half8*)&Xs[w * 16 + (lane & 15)][ks * 32 + (lane >> 4) * 8];
#pragma unroll
        for (int f = 0; f < 4; ++f) {
            half8 bb = *(const half8*)(Cb + ((size_t)(h * DH_ + f * 16 + (lane & 15))) * DH_
                                       + ks * 32 + (lane >> 4) * 8);
            acc[f] = __builtin_amdgcn_mfma_f32_16x16x32_f16(a, bb, acc[f], 0, 0, 0);
        }
    }
    int rb = w * 16 + ((lane >> 4) << 2);
#pragma unroll
    for (int f = 0; f < 4; ++f) {
        int col = f * 16 + (lane & 15);
#pragma unroll
        for (int j = 0; j < 4; ++j)
            Xc[((size_t)bh * N_ + n0 + rb + j) * DH_ + col] = (_Float16)acc[f][j];
    }

    // transpose: lane-permuted d => row-uniform LDS reads (conflict-free)
    {
        int d = (lane & 3) * 16 + (lane >> 2);
        __align__(16) _Float16 tmp[16];
#pragma unroll
        for (int i = 0; i < 16; ++i) tmp[i] = Xs[w * 16 + i][d];
        _Float16* dst = XpT + ((size_t)bh * DH_ + d) * N_ + n0 + w * 16;
        *(half8*)dst = *(half8*)tmp;
        *(half8*)(dst + 8) = *(half8*)(tmp + 8);
    }
}

// ---------------- kernel 4: fused masked-tanh attention (hybrid) ----------
// per block: (b,h,q0), 4 waves x 16 q-rows.
// LDS-staged K/V^T (coalesced, shared by 4 waves) + register-P PV path:
// S^T = mfma(K_frag, Q_frag) -> lane holds P-row for q = lane&15 at
// kv = f*16 + (lane>>4)*4 + j == A-frag layout of mfma_16x16x16f16.
// P never touches LDS; 2 barriers/mt; 1 mask load/mt.
__global__ __launch_bounds__(256) void attn_kernel(const _Float16* __restrict__ Xp,
                                                   const _Float16* __restrict__ Xc,
                                                   const _Float16* __restrict__ XpT,
                                                   const unsigned long long* __restrict__ Abits,
                                                   float* __restrict__ out) {
    __shared__ _Float16 Kb[64][72];   // Kb[kv][d]  (A-frags of S^T)
    __shared__ _Float16 Vt[64][72];   // Vt[d][kv]  (B-frags of PV)

    int tid = threadIdx.x;
    int lane = tid & 63, w = tid >> 6;
    int hi = lane >> 4;
    int c16 = lane & 15;
    int blk = blockIdx.x;
    int bh = blk >> 4;
    int q0 = (blk & 15) * 64;
    int b = bh >> 3, h = bh & 7;

    // Q fragments (B-operand of S^T): row q = q0 + w*16 + c16 of Xc
    const _Float16* qbase = Xc + ((size_t)bh * N_ + q0 + w * 16 + c16) * DH_ + hi * 8;
    half8 qa0 = *(const half8*)qbase;
    half8 qa1 = *(const half8*)(qbase + 32);

    int r = tid >> 2, q = tid & 3;
    const unsigned long long* mbase = Abits + ((size_t)b * N_ + q0 + w * 16 + c16) * 16;

    f32x4 oacc[4] = {{0,0,0,0},{0,0,0,0},{0,0,0,0},{0,0,0,0}};

    for (int mt = 0; mt < 16; ++mt) {
        __syncthreads();   // protect Kb/Vt from previous iteration's reads
        // stage K rows (linear from Xp) and V^T rows (linear from XpT)
        const half8* ksrc = (const half8*)(Xp + ((size_t)bh * N_ + mt * 64 + r) * DH_ + q * 16);
        half8 k0 = ksrc[0], k1 = ksrc[1];
        const half8* vsrc = (const half8*)(XpT + ((size_t)bh * DH_ + r) * N_ + mt * 64 + q * 16);
        half8 v0 = vsrc[0], v1 = vsrc[1];
        *(half8*)&Kb[r][q * 16] = k0;
        *(half8*)&Kb[r][q * 16 + 8] = k1;
        *(half8*)&Vt[r][q * 16] = v0;
        *(half8*)&Vt[r][q * 16 + 8] = v1;
        __syncthreads();

        // S^T = K @ Q^T : A = K rows (kv = f*16 + c16) from LDS, B = Q regs
        f32x4 s[4] = {{0,0,0,0},{0,0,0,0},{0,0,0,0},{0,0,0,0}};
#pragma unroll
        for (int f = 0; f < 4; ++f) {
            half8 kb0 = *(const half8*)&Kb[f * 16 + c16][hi * 8];
            half8 kb1 = *(const half8*)&Kb[f * 16 + c16][32 + hi * 8];
            s[f] = __builtin_amdgcn_mfma_f32_16x16x32_f16(kb0, qa0, s[f], 0, 0, 0);
            s[f] = __builtin_amdgcn_mfma_f32_16x16x32_f16(kb1, qa1, s[f], 0, 0, 0);
        }

        // mask word: one u64 per q-row per mt; bit index = f*16 + hi*4 + j
        unsigned long long m64 = mbase[mt] >> (hi * 4);
        unsigned mlo = (unsigned)m64;
        unsigned mhi32 = (unsigned)(m64 >> 32);

        // tanh + mask + pack into PV A-fragments (all in registers)
        half4 pa[4];
#pragma unroll
        for (int f = 0; f < 4; ++f) {
            unsigned dw = (f & 2) ? mhi32 : mlo;
            int bb = (f & 1) * 16;
            float t0 = tanh_e(s[f][0]) * (float)((dw >> bb) & 1u);
            float t1 = tanh_e(s[f][1]) * (float)((dw >> (bb + 1)) & 1u);
            float t2 = tanh_e(s[f][2]) * (float)((dw >> (bb + 2)) & 1u);
            float t3 = tanh_e(s[f][3]) * (float)((dw >> (bb + 3)) & 1u);
            pa[f] = pack4(t0, t1, t2, t3);
        }

        // O += P @ V  (16 x mfma_16x16x16f16; B-frags = half4 reads from Vt)
#pragma unroll
        for (int f = 0; f < 4; ++f) {
            half4 vf0 = *(const half4*)&Vt[c16     ][f * 16 + hi * 4];
            half4 vf1 = *(const half4*)&Vt[16 + c16][f * 16 + hi * 4];
            half4 vf2 = *(const half4*)&Vt[32 + c16][f * 16 + hi * 4];
            half4 vf3 = *(const half4*)&Vt[48 + c16][f * 16 + hi * 4];
            oacc[0] = __builtin_amdgcn_mfma_f32_16x16x16f16(pa[f], vf0, oacc[0], 0, 0, 0);
            oacc[1] = __builtin_amdgcn_mfma_f32_16x16x16f16(pa[f], vf1, oacc[1], 0, 0, 0);
            oacc[2] = __builtin_amdgcn_mfma_f32_16x16x16f16(pa[f], vf2, oacc[2], 0, 0, 0);
            oacc[3] = __builtin_amdgcn_mfma_f32_16x16x16f16(pa[f], vf3, oacc[3], 0, 0, 0);
        }
    }

    // epilogue: relu, coalesced f32 writes; oacc row q = w*16+hi*4+j, col = d
    int rb = w * 16 + hi * 4;
#pragma unroll
    for (int fo = 0; fo < 4; ++fo) {
        int col = h * DH_ + fo * 16 + c16;
#pragma unroll
        for (int j = 0; j < 4; ++j) {
            out[((size_t)b * N_ + q0 + rb + j) * 512 + col] = fmaxf(oacc[fo][j], 0.f);
        }
    }
}

extern "C" void kernel_launch(void* const* d_in, const int* in_sizes, int n_in,
                              void* d_out, int out_size, void* d_ws, size_t ws_size,
                              hipStream_t stream) {
    const float* X  = (const float*)d_in[0];
    const float* A  = (const float*)d_in[1];
    const float* Wp = (const float*)d_in[2];
    const float* bp = (const float*)d_in[3];
    const float* C  = (const float*)d_in[4];
    float* out = (float*)d_out;

    char* ws = (char*)d_ws;
    unsigned long long* Abits = (unsigned long long*)ws;               // 4 MB
    _Float16* WT  = (_Float16*)(ws + 4u * 1024 * 1024);                // 512 KB
    _Float16* Cb  = (_Float16*)(ws + 4u * 1024 * 1024 + 512 * 1024);   // 64 KB
    _Float16* Xp  = (_Float16*)(ws + 5u * 1024 * 1024);                // 32 MB
    _Float16* Xc  = (_Float16*)(ws + 37u * 1024 * 1024);               // 32 MB
    _Float16* XpT = (_Float16*)(ws + 69u * 1024 * 1024);               // 32 MB  (end: 101 MB)

    pack_mask<<<(B_ * N_ * N_) / (64 * 4), 256, 0, stream>>>(A, Abits);
    prep_w<<<(H_ * DH_ * DIN_ + H_ * DH_ * DH_ + 255) / 256, 256, 0, stream>>>(Wp, C, WT, Cb);
    proj_gemm<<<B_ * 16 * 2, 256, 0, stream>>>(X, bp, WT, Xp);
    bil_kernel<<<B_ * H_ * 16, 256, 0, stream>>>(Xp, Cb, Xc, XpT);
    attn_kernel<<<B_ * H_ * 16, 256, 0, stream>>>(Xp, Xc, XpT, Abits, out);
}

// Round 10
// 462.789 us; speedup vs baseline: 2.2512x; 1.0310x over previous
//
#include <hip/hip_runtime.h>
#include <hip/hip_bf16.h>

typedef __attribute__((ext_vector_type(8))) _Float16 half8;
typedef __attribute__((ext_vector_type(4))) _Float16 half4;
typedef __attribute__((ext_vector_type(2))) unsigned uint2v;
typedef __attribute__((ext_vector_type(4))) float f32x4;

#define B_ 32
#define N_ 1024
#define DIN_ 512
#define H_ 8
#define DH_ 64

// tanh(x) = 1 - 2/(exp(2x)+1); inf/denorm behavior gives exact +-1 saturation,
// tanh(0) == 0 exactly. 3 VALU + 2 trans, no clamp needed.
__device__ __forceinline__ float tanh_e(float x) {
    float e = __builtin_amdgcn_exp2f(x * 2.885390081777927f);  // exp(2x)
    float r = __builtin_amdgcn_rcpf(e + 1.f);
    return fmaf(-2.f, r, 1.f);
}

// pack 4 f32 -> half4 via v_cvt_pkrtz (1 op per pair)
__device__ __forceinline__ half4 pack4(float a, float b, float c, float d) {
    auto lo = __builtin_amdgcn_cvt_pkrtz(a, b);
    auto hi = __builtin_amdgcn_cvt_pkrtz(c, d);
    uint2v u = { __builtin_bit_cast(unsigned, lo), __builtin_bit_cast(unsigned, hi) };
    return __builtin_bit_cast(half4, u);
}

// ---------------- kernel 1: pack adjacency into bitmask -------------------
// A: [B,N,N] f32 of {0,1}  ->  Abits: [B*N][16] u64 (bit m&63 of word m>>6)
__global__ __launch_bounds__(256) void pack_mask(const float* __restrict__ A,
                                                 unsigned long long* __restrict__ Abits) {
    int tid = blockIdx.x * 256 + threadIdx.x;
    int wave = tid >> 6;
    int lane = threadIdx.x & 63;
    float a = A[(size_t)wave * 64 + lane];
    unsigned long long m = __ballot(a != 0.f);
    if (lane == 0) Abits[wave] = m;
}

// ---------------- kernel 2: prep weights ----------------------------------
// WTf frag-major: block (h,kc,ks,f) of 512 halves; element (lane,j) holds
// Wp[h][k = kc*64+ks*32+(lane>>4)*8+j][n = f*16+(lane&15)].
// A wave's B-fragment load = contiguous 1 KB.  Cb: [H][DH][DH] f16.
__global__ __launch_bounds__(256) void prep_w(const float* __restrict__ Wp,
                                              const float* __restrict__ C,
                                              _Float16* __restrict__ WTf,
                                              _Float16* __restrict__ Cb) {
    int gid = blockIdx.x * 256 + threadIdx.x;
    if (gid < H_ * DH_ * DIN_) {
        int blk = gid >> 9;          // (h,kc,ks,f)
        int inner = gid & 511;       // lane*8 + j
        int f = blk & 3, ks = (blk >> 2) & 1, kc = (blk >> 3) & 7, h = blk >> 6;
        int l = inner >> 3, j = inner & 7;
        int c16 = l & 15, hi = l >> 4;
        int n = f * 16 + c16;
        int k = kc * 64 + ks * 32 + hi * 8 + j;
        WTf[gid] = (_Float16)Wp[((size_t)(h * DIN_ + k)) * DH_ + n];
    } else {
        int cid = gid - H_ * DH_ * DIN_;
        if (cid < H_ * DH_ * DH_) Cb[cid] = (_Float16)C[cid];
    }
}

// ---------------- kernel 3: projection GEMM (all 4 heads per block) -------
// block = (b, n0, half): 64 rows x 256 cols (4 heads, 1 head per wave).
// X tile staged once in LDS (f16); W fragments = coalesced 1 KB loads (WTf).
__global__ __launch_bounds__(256) void proj_gemm(const float* __restrict__ X,
                                                 const float* __restrict__ bp,
                                                 const _Float16* __restrict__ WTf,
                                                 _Float16* __restrict__ Xp) {
    __shared__ _Float16 Xb[64][72];

    int tid = threadIdx.x;
    int lane = tid & 63, w = tid >> 6;
    int blk = blockIdx.x;
    int b = blk >> 5;
    int n0 = ((blk >> 1) & 15) * 64;
    int h = (blk & 1) * 4 + w;       // head handled by this wave

    int r = tid >> 2, q = tid & 3;
    const float* xrow = X + ((size_t)b * N_ + n0 + r) * DIN_ + q * 16;
    const _Float16* wbase = WTf + (size_t)h * 32768 + lane * 8;

    f32x4 acc[4][4] = {};

    for (int kc = 0; kc < 8; ++kc) {
        // stage X[64][64] chunk -> f16
        float4 v0 = *(const float4*)(xrow + kc * 64 + 0);
        float4 v1 = *(const float4*)(xrow + kc * 64 + 4);
        float4 v2 = *(const float4*)(xrow + kc * 64 + 8);
        float4 v3 = *(const float4*)(xrow + kc * 64 + 12);
        half8 h0 = {(_Float16)v0.x, (_Float16)v0.y, (_Float16)v0.z, (_Float16)v0.w,
                    (_Float16)v1.x, (_Float16)v1.y, (_Float16)v1.z, (_Float16)v1.w};
        half8 h1 = {(_Float16)v2.x, (_Float16)v2.y, (_Float16)v2.z, (_Float16)v2.w,
                    (_Float16)v3.x, (_Float16)v3.y, (_Float16)v3.z, (_Float16)v3.w};
        *(half8*)&Xb[r][q * 16] = h0;
        *(half8*)&Xb[r][q * 16 + 8] = h1;
        __syncthreads();

#pragma unroll
        for (int ks = 0; ks < 2; ++ks) {
            half8 a[4];
#pragma unroll
            for (int m = 0; m < 4; ++m)
                a[m] = *(const half8*)&Xb[m * 16 + (lane & 15)][ks * 32 + (lane >> 4) * 8];
#pragma unroll
            for (int f = 0; f < 4; ++f) {
                half8 bb = *(const half8*)(wbase + (((kc * 2 + ks) * 4 + f) << 9));
#pragma unroll
                for (int m = 0; m < 4; ++m)
                    acc[m][f] = __builtin_amdgcn_mfma_f32_16x16x32_f16(a[m], bb, acc[m][f], 0, 0, 0);
            }
        }
        __syncthreads();
    }

    // epilogue: bias + f16 write (coalesced 32B segments per 16-lane group)
    size_t bh = (size_t)(b * 8 + h);
#pragma unroll
    for (int f = 0; f < 4; ++f) {
        int col = f * 16 + (lane & 15);
        float bias = bp[h * 64 + col];
#pragma unroll
        for (int m = 0; m < 4; ++m) {
            int row = m * 16 + ((lane >> 4) << 2);
#pragma unroll
            for (int j = 0; j < 4; ++j) {
                Xp[(bh * N_ + n0 + row + j) * DH_ + col] = (_Float16)(acc[m][f][j] + bias);
            }
        }
    }
}

// ---------------- kernel 3b: bilinear + transpose -------------------------
// per block (bh, n0): Xc = Xp_tile @ C^T ; XpT[bh][d][n] = Xp[bh][n][d]
// XpT writes go via XsT (LDS) so each global write is 128 B contiguous/8 lanes.
__global__ __launch_bounds__(256) void bil_kernel(const _Float16* __restrict__ Xp,
                                                  const _Float16* __restrict__ Cb,
                                                  _Float16* __restrict__ Xc,
                                                  _Float16* __restrict__ XpT) {
    __shared__ _Float16 Xs[64][72];
    __shared__ _Float16 XsT[64][72];

    int tid = threadIdx.x;
    int lane = tid & 63, w = tid >> 6;
    int blk = blockIdx.x;
    int bh = blk >> 4;
    int n0 = (blk & 15) * 64;
    int h = bh & 7;

    int r = tid >> 2, q = tid & 3;
    const half8* src = (const half8*)(Xp + ((size_t)bh * N_ + n0 + r) * DH_ + q * 16);
    *(half8*)&Xs[r][q * 16] = src[0];
    *(half8*)&Xs[r][q * 16 + 8] = src[1];
    __syncthreads();

    // bilinear: rows w*16..w*16+15
    f32x4 acc[4] = {{0,0,0,0},{0,0,0,0},{0,0,0,0},{0,0,0,0}};
#pragma unroll
    for (int ks = 0; ks < 2; ++ks) {
        half8 a = *(const half8*)&Xs[w * 16 + (lane & 15)][ks * 32 + (lane >> 4) * 8];
#pragma unroll
        for (int f = 0; f < 4; ++f) {
            half8 bb = *(const half8*)(Cb + ((size_t)(h * DH_ + f * 16 + (lane & 15))) * DH_
                                       + ks * 32 + (lane >> 4) * 8);
            acc[f] = __builtin_amdgcn_mfma_f32_16x16x32_f16(a, bb, acc[f], 0, 0, 0);
        }
    }
    int rb = w * 16 + ((lane >> 4) << 2);
#pragma unroll
    for (int f = 0; f < 4; ++f) {
        int col = f * 16 + (lane & 15);
#pragma unroll
        for (int j = 0; j < 4; ++j)
            Xc[((size_t)bh * N_ + n0 + rb + j) * DH_ + col] = (_Float16)acc[f][j];
    }

    // transpose into XsT (lane-permuted d => conflict-light column reads)
    {
        int d = (lane & 3) * 16 + (lane >> 2);
        __align__(16) _Float16 tmp[16];
#pragma unroll
        for (int i = 0; i < 16; ++i) tmp[i] = Xs[w * 16 + i][d];
        *(half8*)&XsT[d][w * 16] = *(half8*)tmp;
        *(half8*)&XsT[d][w * 16 + 8] = *(half8*)(tmp + 8);
    }
    __syncthreads();

    // coalesced XpT writes: 8 lanes cover one 128 B d-row; 2 rows per thread
    {
        int d = tid >> 3;            // 0..31
        int c8 = (tid & 7) * 8;
        *(half8*)(XpT + ((size_t)bh * DH_ + d) * N_ + n0 + c8) = *(const half8*)&XsT[d][c8];
        *(half8*)(XpT + ((size_t)bh * DH_ + d + 32) * N_ + n0 + c8) = *(const half8*)&XsT[d + 32][c8];
    }
}

// ---------------- kernel 4: fused masked-tanh attention (hybrid) ----------
// per block: (b,h,q0), 4 waves x 16 q-rows.
// LDS-staged K/V^T + register-P PV path; async-STAGE: mt+1 loads issued
// right after mt's LDS writes -> latency hides under compute phase.
__global__ __launch_bounds__(256) void attn_kernel(const _Float16* __restrict__ Xp,
                                                   const _Float16* __restrict__ Xc,
                                                   const _Float16* __restrict__ XpT,
                                                   const unsigned long long* __restrict__ Abits,
                                                   float* __restrict__ out) {
    __shared__ _Float16 Kb[64][72];   // Kb[kv][d]  (A-frags of S^T)
    __shared__ _Float16 Vt[64][72];   // Vt[d][kv]  (B-frags of PV)

    int tid = threadIdx.x;
    int lane = tid & 63, w = tid >> 6;
    int hi = lane >> 4;
    int c16 = lane & 15;
    int blk = blockIdx.x;
    int bh = blk >> 4;
    int q0 = (blk & 15) * 64;
    int b = bh >> 3, h = bh & 7;

    // Q fragments (B-operand of S^T): row q = q0 + w*16 + c16 of Xc
    const _Float16* qbase = Xc + ((size_t)bh * N_ + q0 + w * 16 + c16) * DH_ + hi * 8;
    half8 qa0 = *(const half8*)qbase;
    half8 qa1 = *(const half8*)(qbase + 32);

    int r = tid >> 2, q = tid & 3;
    const unsigned long long* mbase = Abits + ((size_t)b * N_ + q0 + w * 16 + c16) * 16;

    f32x4 oacc[4] = {{0,0,0,0},{0,0,0,0},{0,0,0,0},{0,0,0,0}};

    // prologue: loads for mt=0
    const _Float16* kptr = Xp + ((size_t)bh * N_ + r) * DH_ + q * 16;
    const _Float16* vptr = XpT + ((size_t)bh * DH_ + r) * N_ + q * 16;
    half8 k0 = *(const half8*)kptr, k1 = *(const half8*)(kptr + 8);
    half8 v0 = *(const half8*)vptr, v1 = *(const half8*)(vptr + 8);
    unsigned long long mcur = mbase[0];
    unsigned long long mnext = 0;

    for (int mt = 0; mt < 16; ++mt) {
        __syncthreads();   // all waves done reading Kb/Vt of mt-1
        *(half8*)&Kb[r][q * 16] = k0;
        *(half8*)&Kb[r][q * 16 + 8] = k1;
        *(half8*)&Vt[r][q * 16] = v0;
        *(half8*)&Vt[r][q * 16 + 8] = v1;
        if (mt < 15) {   // issue mt+1 loads now; consumed next iteration
            const _Float16* kn = kptr + (size_t)(mt + 1) * 64 * DH_;
            const _Float16* vn = vptr + (mt + 1) * 64;
            k0 = *(const half8*)kn; k1 = *(const half8*)(kn + 8);
            v0 = *(const half8*)vn; v1 = *(const half8*)(vn + 8);
            mnext = mbase[mt + 1];
        }
        __syncthreads();

        // S^T = K @ Q^T : A = K rows (kv = f*16 + c16) from LDS, B = Q regs
        f32x4 s[4] = {{0,0,0,0},{0,0,0,0},{0,0,0,0},{0,0,0,0}};
#pragma unroll
        for (int f = 0; f < 4; ++f) {
            half8 kb0 = *(const half8*)&Kb[f * 16 + c16][hi * 8];
            half8 kb1 = *(const half8*)&Kb[f * 16 + c16][32 + hi * 8];
            s[f] = __builtin_amdgcn_mfma_f32_16x16x32_f16(kb0, qa0, s[f], 0, 0, 0);
            s[f] = __builtin_amdgcn_mfma_f32_16x16x32_f16(kb1, qa1, s[f], 0, 0, 0);
        }

        // mask word: bit index = f*16 + hi*4 + j
        unsigned long long m64 = mcur >> (hi * 4);
        unsigned mlo = (unsigned)m64;
        unsigned mhi32 = (unsigned)(m64 >> 32);

        // tanh + mask + pack into PV A-fragments (all in registers)
        half4 pa[4];
#pragma unroll
        for (int f = 0; f < 4; ++f) {
            unsigned dw = (f & 2) ? mhi32 : mlo;
            int bb = (f & 1) * 16;
            float t0 = tanh_e(s[f][0]) * (float)((dw >> bb) & 1u);
            float t1 = tanh_e(s[f][1]) * (float)((dw >> (bb + 1)) & 1u);
            float t2 = tanh_e(s[f][2]) * (float)((dw >> (bb + 2)) & 1u);
            float t3 = tanh_e(s[f][3]) * (float)((dw >> (bb + 3)) & 1u);
            pa[f] = pack4(t0, t1, t2, t3);
        }

        // O += P @ V  (16 x mfma_16x16x16f16; B-frags = half4 reads from Vt)
#pragma unroll
        for (int f = 0; f < 4; ++f) {
            half4 vf0 = *(const half4*)&Vt[c16     ][f * 16 + hi * 4];
            half4 vf1 = *(const half4*)&Vt[16 + c16][f * 16 + hi * 4];
            half4 vf2 = *(const half4*)&Vt[32 + c16][f * 16 + hi * 4];
            half4 vf3 = *(const half4*)&Vt[48 + c16][f * 16 + hi * 4];
            oacc[0] = __builtin_amdgcn_mfma_f32_16x16x16f16(pa[f], vf0, oacc[0], 0, 0, 0);
            oacc[1] = __builtin_amdgcn_mfma_f32_16x16x16f16(pa[f], vf1, oacc[1], 0, 0, 0);
            oacc[2] = __builtin_amdgcn_mfma_f32_16x16x16f16(pa[f], vf2, oacc[2], 0, 0, 0);
            oacc[3] = __builtin_amdgcn_mfma_f32_16x16x16f16(pa[f], vf3, oacc[3], 0, 0, 0);
        }
        mcur = mnext;
    }

    // epilogue: relu, coalesced f32 writes; oacc row q = w*16+hi*4+j, col = d
    int rb = w * 16 + hi * 4;
#pragma unroll
    for (int fo = 0; fo < 4; ++fo) {
        int col = h * DH_ + fo * 16 + c16;
#pragma unroll
        for (int j = 0; j < 4; ++j) {
            out[((size_t)b * N_ + q0 + rb + j) * 512 + col] = fmaxf(oacc[fo][j], 0.f);
        }
    }
}

extern "C" void kernel_launch(void* const* d_in, const int* in_sizes, int n_in,
                              void* d_out, int out_size, void* d_ws, size_t ws_size,
                              hipStream_t stream) {
    const float* X  = (const float*)d_in[0];
    const float* A  = (const float*)d_in[1];
    const float* Wp = (const float*)d_in[2];
    const float* bp = (const float*)d_in[3];
    const float* C  = (const float*)d_in[4];
    float* out = (float*)d_out;

    char* ws = (char*)d_ws;
    unsigned long long* Abits = (unsigned long long*)ws;               // 4 MB
    _Float16* WTf = (_Float16*)(ws + 4u * 1024 * 1024);                // 512 KB
    _Float16* Cb  = (_Float16*)(ws + 4u * 1024 * 1024 + 512 * 1024);   // 64 KB
    _Float16* Xp  = (_Float16*)(ws + 5u * 1024 * 1024);                // 32 MB
    _Float16* Xc  = (_Float16*)(ws + 37u * 1024 * 1024);               // 32 MB
    _Float16* XpT = (_Float16*)(ws + 69u * 1024 * 1024);               // 32 MB  (end: 101 MB)

    pack_mask<<<(B_ * N_ * N_) / (64 * 4), 256, 0, stream>>>(A, Abits);
    prep_w<<<(H_ * DH_ * DIN_ + H_ * DH_ * DH_ + 255) / 256, 256, 0, stream>>>(Wp, C, WTf, Cb);
    proj_gemm<<<B_ * 16 * 2, 256, 0, stream>>>(X, bp, WTf, Xp);
    bil_kernel<<<B_ * H_ * 16, 256, 0, stream>>>(Xp, Cb, Xc, XpT);
    attn_kernel<<<B_ * H_ * 16, 256, 0, stream>>>(Xp, Xc, XpT, Abits, out);
}

// Round 11
// 446.992 us; speedup vs baseline: 2.3308x; 1.0353x over previous
//
#include <hip/hip_runtime.h>
#include <hip/hip_bf16.h>

typedef __attribute__((ext_vector_type(8))) _Float16 half8;
typedef __attribute__((ext_vector_type(4))) _Float16 half4;
typedef __attribute__((ext_vector_type(2))) unsigned uint2v;
typedef __attribute__((ext_vector_type(4))) float f32x4;

#define B_ 32
#define N_ 1024
#define DIN_ 512
#define H_ 8
#define DH_ 64

// tanh(x) = 1 - 2/(exp(2x)+1); inf/denorm behavior gives exact +-1 saturation,
// tanh(0) == 0 exactly (rcp(2.0) = 0.5 exact) -> mask can be applied to the
// INPUT (s = bit ? s : 0) and the output needs no further masking.
__device__ __forceinline__ float tanh_e(float x) {
    float e = __builtin_amdgcn_exp2f(x * 2.885390081777927f);  // exp(2x)
    float r = __builtin_amdgcn_rcpf(e + 1.f);
    return fmaf(-2.f, r, 1.f);
}

// pack 4 f32 -> half4 via v_cvt_pkrtz (1 op per pair)
__device__ __forceinline__ half4 pack4(float a, float b, float c, float d) {
    auto lo = __builtin_amdgcn_cvt_pkrtz(a, b);
    auto hi = __builtin_amdgcn_cvt_pkrtz(c, d);
    uint2v u = { __builtin_bit_cast(unsigned, lo), __builtin_bit_cast(unsigned, hi) };
    return __builtin_bit_cast(half4, u);
}

// ---------------- kernel 1: pack adjacency into bitmask -------------------
// A: [B,N,N] f32 of {0,1}  ->  Abits: [B*N][16] u64 (bit m&63 of word m>>6)
__global__ __launch_bounds__(256) void pack_mask(const float* __restrict__ A,
                                                 unsigned long long* __restrict__ Abits) {
    int tid = blockIdx.x * 256 + threadIdx.x;
    int wave = tid >> 6;
    int lane = threadIdx.x & 63;
    float a = A[(size_t)wave * 64 + lane];
    unsigned long long m = __ballot(a != 0.f);
    if (lane == 0) Abits[wave] = m;
}

// ---------------- kernel 2: prep weights ----------------------------------
// WTf frag-major: block (h,kc,ks,f) of 512 halves; element (lane,j) holds
// Wp[h][k = kc*64+ks*32+(lane>>4)*8+j][n = f*16+(lane&15)].
// A wave's B-fragment load = contiguous 1 KB.  Cb: [H][DH][DH] f16.
__global__ __launch_bounds__(256) void prep_w(const float* __restrict__ Wp,
                                              const float* __restrict__ C,
                                              _Float16* __restrict__ WTf,
                                              _Float16* __restrict__ Cb) {
    int gid = blockIdx.x * 256 + threadIdx.x;
    if (gid < H_ * DH_ * DIN_) {
        int blk = gid >> 9;          // (h,kc,ks,f)
        int inner = gid & 511;       // lane*8 + j
        int f = blk & 3, ks = (blk >> 2) & 1, kc = (blk >> 3) & 7, h = blk >> 6;
        int l = inner >> 3, j = inner & 7;
        int c16 = l & 15, hi = l >> 4;
        int n = f * 16 + c16;
        int k = kc * 64 + ks * 32 + hi * 8 + j;
        WTf[gid] = (_Float16)Wp[((size_t)(h * DIN_ + k)) * DH_ + n];
    } else {
        int cid = gid - H_ * DH_ * DIN_;
        if (cid < H_ * DH_ * DH_) Cb[cid] = (_Float16)C[cid];
    }
}

// ---------------- kernel 3: projection + bilinear + transpose (fused) -----
// block = (b, n0, half): 64 rows x 256 cols (4 heads, 1 head per wave).
// Main loop: Xp = X@Wp (X staged once in LDS; WTf frag-major coalesced).
// Epilogue per wave (own head): Xp write + LDS tile S[w], bilinear Xc,
// register transpose -> XpT.  bil_kernel eliminated (no Xp re-read).
__global__ __launch_bounds__(256) void proj_gemm(const float* __restrict__ X,
                                                 const float* __restrict__ bp,
                                                 const _Float16* __restrict__ WTf,
                                                 const _Float16* __restrict__ Cb,
                                                 _Float16* __restrict__ Xp,
                                                 _Float16* __restrict__ Xc,
                                                 _Float16* __restrict__ XpT) {
    __shared__ _Float16 S[4][64][72];   // S[0] doubles as the X staging tile

    int tid = threadIdx.x;
    int lane = tid & 63, w = tid >> 6;
    int blk = blockIdx.x;
    int b = blk >> 5;
    int n0 = ((blk >> 1) & 15) * 64;
    int h = (blk & 1) * 4 + w;       // head handled by this wave
    int c16 = lane & 15, hi = lane >> 4;

    int r = tid >> 2, q = tid & 3;
    const float* xrow = X + ((size_t)b * N_ + n0 + r) * DIN_ + q * 16;
    const _Float16* wbase = WTf + (size_t)h * 32768 + lane * 8;

    f32x4 acc[4][4] = {};

    for (int kc = 0; kc < 8; ++kc) {
        // stage X[64][64] chunk -> f16 into S[0]
        float4 v0 = *(const float4*)(xrow + kc * 64 + 0);
        float4 v1 = *(const float4*)(xrow + kc * 64 + 4);
        float4 v2 = *(const float4*)(xrow + kc * 64 + 8);
        float4 v3 = *(const float4*)(xrow + kc * 64 + 12);
        half8 h0 = {(_Float16)v0.x, (_Float16)v0.y, (_Float16)v0.z, (_Float16)v0.w,
                    (_Float16)v1.x, (_Float16)v1.y, (_Float16)v1.z, (_Float16)v1.w};
        half8 h1 = {(_Float16)v2.x, (_Float16)v2.y, (_Float16)v2.z, (_Float16)v2.w,
                    (_Float16)v3.x, (_Float16)v3.y, (_Float16)v3.z, (_Float16)v3.w};
        *(half8*)&S[0][r][q * 16] = h0;
        *(half8*)&S[0][r][q * 16 + 8] = h1;
        __syncthreads();

#pragma unroll
        for (int ks = 0; ks < 2; ++ks) {
            half8 a[4];
#pragma unroll
            for (int m = 0; m < 4; ++m)
                a[m] = *(const half8*)&S[0][m * 16 + c16][ks * 32 + hi * 8];
#pragma unroll
            for (int f = 0; f < 4; ++f) {
                half8 bb = *(const half8*)(wbase + (((kc * 2 + ks) * 4 + f) << 9));
#pragma unroll
                for (int m = 0; m < 4; ++m)
                    acc[m][f] = __builtin_amdgcn_mfma_f32_16x16x32_f16(a[m], bb, acc[m][f], 0, 0, 0);
            }
        }
        __syncthreads();
    }

    // epilogue A: bias; write Xp (global) + per-wave LDS tile S[w]
    size_t bh = (size_t)(b * 8 + h);
#pragma unroll
    for (int f = 0; f < 4; ++f) {
        int col = f * 16 + c16;
        float bias = bp[h * 64 + col];
#pragma unroll
        for (int m = 0; m < 4; ++m) {
            int row = m * 16 + (hi << 2);
#pragma unroll
            for (int j = 0; j < 4; ++j) {
                _Float16 v = (_Float16)(acc[m][f][j] + bias);
                Xp[(bh * N_ + n0 + row + j) * DH_ + col] = v;
                S[w][row + j][col] = v;
            }
        }
    }
    // only this wave reads S[w] below -> intra-wave LDS ordering suffices

    // epilogue B: bilinear Xc = S[w] @ C^T  (32 MFMA per wave)
    {
        f32x4 accc[4][4] = {};
#pragma unroll
        for (int ks = 0; ks < 2; ++ks) {
            half8 a[4];
#pragma unroll
            for (int m = 0; m < 4; ++m)
                a[m] = *(const half8*)&S[w][m * 16 + c16][ks * 32 + hi * 8];
#pragma unroll
            for (int f = 0; f < 4; ++f) {
                half8 bb = *(const half8*)(Cb + ((size_t)(h * DH_ + f * 16 + c16)) * DH_
                                           + ks * 32 + hi * 8);
#pragma unroll
                for (int m = 0; m < 4; ++m)
                    accc[m][f] = __builtin_amdgcn_mfma_f32_16x16x32_f16(a[m], bb, accc[m][f], 0, 0, 0);
            }
        }
#pragma unroll
        for (int f = 0; f < 4; ++f) {
            int col = f * 16 + c16;
#pragma unroll
            for (int m = 0; m < 4; ++m) {
                int row = m * 16 + (hi << 2);
#pragma unroll
                for (int j = 0; j < 4; ++j)
                    Xc[(bh * N_ + n0 + row + j) * DH_ + col] = (_Float16)(accc[m][f][j]);
            }
        }
    }

    // epilogue C: transpose S[w] -> XpT[bh][d][n0..]  (lane-permuted d =>
    // row-uniform LDS reads, conflict-free; 4 row-groups of 16)
    {
        int d = (lane & 3) * 16 + (lane >> 2);
#pragma unroll
        for (int g = 0; g < 4; ++g) {
            __align__(16) _Float16 tmp[16];
#pragma unroll
            for (int i = 0; i < 16; ++i) tmp[i] = S[w][g * 16 + i][d];
            _Float16* dst = XpT + (bh * DH_ + d) * N_ + n0 + g * 16;
            *(half8*)dst = *(half8*)tmp;
            *(half8*)(dst + 8) = *(half8*)(tmp + 8);
        }
    }
}

// ---------------- kernel 4: fused masked-tanh attention (hybrid) ----------
// per block: (b,h,q0), 4 waves x 16 q-rows.  XCD-swizzled blockIdx so the
// 16 q-tiles of one bh share an XCD's L2 (K/V panel fetched once per XCD).
// LDS-staged K/V^T + register-P PV path; mask applied to S before tanh.
__global__ __launch_bounds__(256) void attn_kernel(const _Float16* __restrict__ Xp,
                                                   const _Float16* __restrict__ Xc,
                                                   const _Float16* __restrict__ XpT,
                                                   const unsigned long long* __restrict__ Abits,
                                                   float* __restrict__ out) {
    __shared__ _Float16 Kb[64][72];   // Kb[kv][d]  (A-frags of S^T)
    __shared__ _Float16 Vt[64][72];   // Vt[d][kv]  (B-frags of PV)

    int tid = threadIdx.x;
    int lane = tid & 63, w = tid >> 6;
    int hi = lane >> 4;
    int c16 = lane & 15;
    // XCD-aware swizzle (bijective: 4096 % 8 == 0): consecutive o on one XCD
    int o = (blockIdx.x & 7) * 512 + (blockIdx.x >> 3);
    int bh = o >> 4;
    int q0 = (o & 15) * 64;
    int b = bh >> 3, h = bh & 7;

    // Q fragments (B-operand of S^T): row q = q0 + w*16 + c16 of Xc
    const _Float16* qbase = Xc + ((size_t)bh * N_ + q0 + w * 16 + c16) * DH_ + hi * 8;
    half8 qa0 = *(const half8*)qbase;
    half8 qa1 = *(const half8*)(qbase + 32);

    int r = tid >> 2, q = tid & 3;
    const unsigned long long* mbase = Abits + ((size_t)b * N_ + q0 + w * 16 + c16) * 16;

    f32x4 oacc[4] = {{0,0,0,0},{0,0,0,0},{0,0,0,0},{0,0,0,0}};

    const _Float16* kptr = Xp + ((size_t)bh * N_ + r) * DH_ + q * 16;
    const _Float16* vptr = XpT + ((size_t)bh * DH_ + r) * N_ + q * 16;

    for (int mt = 0; mt < 16; ++mt) {
        __syncthreads();   // all waves done reading Kb/Vt of mt-1
        const _Float16* kn = kptr + (size_t)mt * 64 * DH_;
        const _Float16* vn = vptr + mt * 64;
        *(half8*)&Kb[r][q * 16]     = *(const half8*)kn;
        *(half8*)&Kb[r][q * 16 + 8] = *(const half8*)(kn + 8);
        *(half8*)&Vt[r][q * 16]     = *(const half8*)vn;
        *(half8*)&Vt[r][q * 16 + 8] = *(const half8*)(vn + 8);
        unsigned long long mcur = mbase[mt];
        __syncthreads();

        // S^T = K @ Q^T : A = K rows (kv = f*16 + c16) from LDS, B = Q regs
        f32x4 s[4] = {{0,0,0,0},{0,0,0,0},{0,0,0,0},{0,0,0,0}};
#pragma unroll
        for (int f = 0; f < 4; ++f) {
            half8 kb0 = *(const half8*)&Kb[f * 16 + c16][hi * 8];
            half8 kb1 = *(const half8*)&Kb[f * 16 + c16][32 + hi * 8];
            s[f] = __builtin_amdgcn_mfma_f32_16x16x32_f16(kb0, qa0, s[f], 0, 0, 0);
            s[f] = __builtin_amdgcn_mfma_f32_16x16x32_f16(kb1, qa1, s[f], 0, 0, 0);
        }

        // mask S before tanh (tanh_e(0)==0 exactly): cmp+cndmask per element
        unsigned long long m64 = mcur >> (hi * 4);
        unsigned mlo = (unsigned)m64;
        unsigned mhi32 = (unsigned)(m64 >> 32);

        half4 pa[4];
#pragma unroll
        for (int f = 0; f < 4; ++f) {
            unsigned dw = (f & 2) ? mhi32 : mlo;
            int bb = (f & 1) * 16;
            float s0 = ((dw >> bb) & 1u)       ? s[f][0] : 0.f;
            float s1 = ((dw >> (bb + 1)) & 1u) ? s[f][1] : 0.f;
            float s2 = ((dw >> (bb + 2)) & 1u) ? s[f][2] : 0.f;
            float s3 = ((dw >> (bb + 3)) & 1u) ? s[f][3] : 0.f;
            pa[f] = pack4(tanh_e(s0), tanh_e(s1), tanh_e(s2), tanh_e(s3));
        }

        // O += P @ V  (16 x mfma_16x16x16f16; B-frags = half4 reads from Vt)
#pragma unroll
        for (int f = 0; f < 4; ++f) {
            half4 vf0 = *(const half4*)&Vt[c16     ][f * 16 + hi * 4];
            half4 vf1 = *(const half4*)&Vt[16 + c16][f * 16 + hi * 4];
            half4 vf2 = *(const half4*)&Vt[32 + c16][f * 16 + hi * 4];
            half4 vf3 = *(const half4*)&Vt[48 + c16][f * 16 + hi * 4];
            oacc[0] = __builtin_amdgcn_mfma_f32_16x16x16f16(pa[f], vf0, oacc[0], 0, 0, 0);
            oacc[1] = __builtin_amdgcn_mfma_f32_16x16x16f16(pa[f], vf1, oacc[1], 0, 0, 0);
            oacc[2] = __builtin_amdgcn_mfma_f32_16x16x16f16(pa[f], vf2, oacc[2], 0, 0, 0);
            oacc[3] = __builtin_amdgcn_mfma_f32_16x16x16f16(pa[f], vf3, oacc[3], 0, 0, 0);
        }
    }

    // epilogue: relu, coalesced f32 writes; oacc row q = w*16+hi*4+j, col = d
    int rb = w * 16 + hi * 4;
#pragma unroll
    for (int fo = 0; fo < 4; ++fo) {
        int col = h * DH_ + fo * 16 + c16;
#pragma unroll
        for (int j = 0; j < 4; ++j) {
            out[((size_t)b * N_ + q0 + rb + j) * 512 + col] = fmaxf(oacc[fo][j], 0.f);
        }
    }
}

extern "C" void kernel_launch(void* const* d_in, const int* in_sizes, int n_in,
                              void* d_out, int out_size, void* d_ws, size_t ws_size,
                              hipStream_t stream) {
    const float* X  = (const float*)d_in[0];
    const float* A  = (const float*)d_in[1];
    const float* Wp = (const float*)d_in[2];
    const float* bp = (const float*)d_in[3];
    const float* C  = (const float*)d_in[4];
    float* out = (float*)d_out;

    char* ws = (char*)d_ws;
    unsigned long long* Abits = (unsigned long long*)ws;               // 4 MB
    _Float16* WTf = (_Float16*)(ws + 4u * 1024 * 1024);                // 512 KB
    _Float16* Cb  = (_Float16*)(ws + 4u * 1024 * 1024 + 512 * 1024);   // 64 KB
    _Float16* Xp  = (_Float16*)(ws + 5u * 1024 * 1024);                // 32 MB
    _Float16* Xc  = (_Float16*)(ws + 37u * 1024 * 1024);               // 32 MB
    _Float16* XpT = (_Float16*)(ws + 69u * 1024 * 1024);               // 32 MB  (end: 101 MB)

    pack_mask<<<(B_ * N_ * N_) / (64 * 4), 256, 0, stream>>>(A, Abits);
    prep_w<<<(H_ * DH_ * DIN_ + H_ * DH_ * DH_ + 255) / 256, 256, 0, stream>>>(Wp, C, WTf, Cb);
    proj_gemm<<<B_ * 16 * 2, 256, 0, stream>>>(X, bp, WTf, Cb, Xp, Xc, XpT);
    attn_kernel<<<B_ * H_ * 16, 256, 0, stream>>>(Xp, Xc, XpT, Abits, out);
}